// Round 4
// baseline (62.764 us; speedup 1.0000x reference)
//
#include <hip/hip_runtime.h>
#include <hip/hip_bf16.h>
#include <math.h>

#define N_Q 2048
#define M_K 1024
#define DIN 128
#define DK  64

typedef __attribute__((ext_vector_type(8))) short short8;
typedef __attribute__((ext_vector_type(4))) float f32x4;

// ---------------------------------------------------------------------------
// Kernel 1: Qp = q@W^T, Kp = k@W^T in fp32; emit bf16 hi/lo split
//   (hi = bf16(x), lo = bf16(x - float(hi))) row-major [row][64], plus
//   fp32 squared norms. 96 blocks x 512 thr; 32 rows/block, 4 rows/wave;
//   W-read amortized over 4 rows (1 distinct b128 + 4 broadcast b128 / 16 FMA).
// ---------------------------------------------------------------------------
__global__ __launch_bounds__(512) void proj_split_kernel(
    const float* __restrict__ q, const float* __restrict__ k,
    const float* __restrict__ W,
    unsigned short* __restrict__ Qh, unsigned short* __restrict__ Ql,
    unsigned short* __restrict__ Kh, unsigned short* __restrict__ Kl,
    float* __restrict__ qn2, float* __restrict__ kn2)
{
    __shared__ float W_lds[DK][DIN + 4];     // stride 132: b128 conflict-free
    __shared__ float row_lds[32][DIN];
    const int tx = threadIdx.x;

    // stage W: 2048 float4s, 4 per thread
    const float4* W4 = (const float4*)W;
    #pragma unroll
    for (int i = 0; i < 4; ++i) {
        int idx = tx + i * 512;
        float4 v = W4[idx];
        int r = idx >> 5, c = (idx & 31) * 4;
        *(float4*)&W_lds[r][c] = v;
    }

    // stage 32 input rows (all-q or all-k per block): 1024 float4s
    const int R0 = blockIdx.x * 32;          // 0..3040
    const bool isQ = (R0 < N_Q);
    const float* src = isQ ? (q + (size_t)R0 * DIN)
                           : (k + (size_t)(R0 - N_Q) * DIN);
    const float4* src4 = (const float4*)src;
    #pragma unroll
    for (int i = 0; i < 2; ++i) {
        int idx = tx + i * 512;
        float4 v = src4[idx];
        int r = idx >> 5, c = (idx & 31) * 4;
        *(float4*)&row_lds[r][c] = v;
    }
    __syncthreads();

    const int wave = tx >> 6, lane = tx & 63;   // lane = output dim o
    float acc[4] = {0.f, 0.f, 0.f, 0.f};
    #pragma unroll
    for (int d = 0; d < DIN; d += 4) {
        float4 wv = *(const float4*)&W_lds[lane][d];
        #pragma unroll
        for (int r = 0; r < 4; ++r) {
            float4 rv = *(const float4*)&row_lds[wave * 4 + r][d];
            acc[r] = fmaf(wv.x, rv.x, acc[r]);
            acc[r] = fmaf(wv.y, rv.y, acc[r]);
            acc[r] = fmaf(wv.z, rv.z, acc[r]);
            acc[r] = fmaf(wv.w, rv.w, acc[r]);
        }
    }

    #pragma unroll
    for (int r = 0; r < 4; ++r) {
        const int row = R0 + wave * 4 + r;      // global row index (q or k space)
        const float v = acc[r];
        __hip_bfloat16 hb = __float2bfloat16(v);
        float hf = __bfloat162float(hb);
        __hip_bfloat16 lb = __float2bfloat16(v - hf);
        float sq = v * v;
        #pragma unroll
        for (int off = 32; off >= 1; off >>= 1)
            sq += __shfl_xor(sq, off, 64);
        if (isQ) {
            Qh[(size_t)row * DK + lane] = *(unsigned short*)&hb;
            Ql[(size_t)row * DK + lane] = *(unsigned short*)&lb;
            if (lane == 0) qn2[row] = sq;
        } else {
            const int m = row - N_Q;
            Kh[(size_t)m * DK + lane] = *(unsigned short*)&hb;
            Kl[(size_t)m * DK + lane] = *(unsigned short*)&lb;
            if (lane == 0) kn2[m] = sq;
        }
    }
}

// ---------------------------------------------------------------------------
// Kernel 2: 128 blocks x 512 thr (8 waves). Block = 16 q-rows x all 1024 m.
// Wave w owns m-strip [128w,128w+128): 8 tiles of 16x16 via
// mfma_f32_16x16x32_bf16, 2 k-steps x 3 split combos = 6 MFMA/tile.
// A/B frags are contiguous 16B chunks of row-major [row][64] bf16 (no LDS).
// C layout: col=lane&15 (m), row=4*(lane>>4)+reg (n)  [m89-verified].
// Epilogue: s=-0.5*sqrt(qn2+kn2-2c) -> row softmax: shfl_xor(1,2,4,8) within
// 16-lane groups + [16][8] LDS cross-wave reduce. Direct dword stores.
// ---------------------------------------------------------------------------
__global__ __launch_bounds__(512) void score_kernel(
    const unsigned short* __restrict__ Qh, const unsigned short* __restrict__ Ql,
    const unsigned short* __restrict__ Kh, const unsigned short* __restrict__ Kl,
    const float* __restrict__ qn2, const float* __restrict__ kn2,
    float* __restrict__ out)
{
    __shared__ float redmax[16][8];
    __shared__ float redsum[16][8];

    const int tx = threadIdx.x;
    const int w = tx >> 6, l = tx & 63;
    const int g = l >> 4, c = l & 15;
    const int n0 = blockIdx.x * 16;

    // A fragments: lane holds Q*[n0+c][8g..8g+7] (k-step 0) / +32 (k-step 1)
    const unsigned short* qrh = Qh + (size_t)(n0 + c) * DK;
    const unsigned short* qrl = Ql + (size_t)(n0 + c) * DK;
    const short8 Ah0 = *(const short8*)(qrh + g * 8);
    const short8 Ah1 = *(const short8*)(qrh + 32 + g * 8);
    const short8 Al0 = *(const short8*)(qrl + g * 8);
    const short8 Al1 = *(const short8*)(qrl + 32 + g * 8);

    float qn[4];
    #pragma unroll
    for (int j = 0; j < 4; ++j) qn[j] = qn2[n0 + 4 * g + j];

    float s[8][4];
    #pragma unroll
    for (int t = 0; t < 8; ++t) {
        const int m = w * 128 + t * 16 + c;
        const unsigned short* krh = Kh + (size_t)m * DK;
        const unsigned short* krl = Kl + (size_t)m * DK;
        short8 Bh0 = *(const short8*)(krh + g * 8);
        short8 Bh1 = *(const short8*)(krh + 32 + g * 8);
        short8 Bl0 = *(const short8*)(krl + g * 8);
        short8 Bl1 = *(const short8*)(krl + 32 + g * 8);

        f32x4 acc = {0.f, 0.f, 0.f, 0.f};
        acc = __builtin_amdgcn_mfma_f32_16x16x32_bf16(Ah0, Bh0, acc, 0, 0, 0);
        acc = __builtin_amdgcn_mfma_f32_16x16x32_bf16(Ah1, Bh1, acc, 0, 0, 0);
        acc = __builtin_amdgcn_mfma_f32_16x16x32_bf16(Ah0, Bl0, acc, 0, 0, 0);
        acc = __builtin_amdgcn_mfma_f32_16x16x32_bf16(Ah1, Bl1, acc, 0, 0, 0);
        acc = __builtin_amdgcn_mfma_f32_16x16x32_bf16(Al0, Bh0, acc, 0, 0, 0);
        acc = __builtin_amdgcn_mfma_f32_16x16x32_bf16(Al1, Bh1, acc, 0, 0, 0);

        const float kn = kn2[m];
        #pragma unroll
        for (int j = 0; j < 4; ++j) {
            float d2 = fmaxf(qn[j] + kn - 2.f * acc[j], 0.f);
            s[t][j] = -0.5f * sqrtf(d2);
        }
    }

    // row max over this wave's 128 cols, then across 8 waves via LDS
    #pragma unroll
    for (int j = 0; j < 4; ++j) {
        float m8 = s[0][j];
        #pragma unroll
        for (int t = 1; t < 8; ++t) m8 = fmaxf(m8, s[t][j]);
        m8 = fmaxf(m8, __shfl_xor(m8, 1, 64));
        m8 = fmaxf(m8, __shfl_xor(m8, 2, 64));
        m8 = fmaxf(m8, __shfl_xor(m8, 4, 64));
        m8 = fmaxf(m8, __shfl_xor(m8, 8, 64));
        if (c == 0) redmax[4 * g + j][w] = m8;
    }
    __syncthreads();

    float mx[4];
    #pragma unroll
    for (int j = 0; j < 4; ++j) {
        float m = redmax[4 * g + j][0];
        #pragma unroll
        for (int ww = 1; ww < 8; ++ww) m = fmaxf(m, redmax[4 * g + j][ww]);
        mx[j] = m;
    }

    // exp + row sum
    #pragma unroll
    for (int j = 0; j < 4; ++j) {
        float t8 = 0.f;
        #pragma unroll
        for (int t = 0; t < 8; ++t) {
            s[t][j] = __expf(s[t][j] - mx[j]);
            t8 += s[t][j];
        }
        t8 += __shfl_xor(t8, 1, 64);
        t8 += __shfl_xor(t8, 2, 64);
        t8 += __shfl_xor(t8, 4, 64);
        t8 += __shfl_xor(t8, 8, 64);
        if (c == 0) redsum[4 * g + j][w] = t8;
    }
    __syncthreads();

    float inv[4];
    #pragma unroll
    for (int j = 0; j < 4; ++j) {
        float t = 0.f;
        #pragma unroll
        for (int ww = 0; ww < 8; ++ww) t += redsum[4 * g + j][ww];
        inv[j] = 1.0f / t;
    }

    #pragma unroll
    for (int t = 0; t < 8; ++t) {
        const int m = w * 128 + t * 16 + c;
        #pragma unroll
        for (int j = 0; j < 4; ++j)
            out[(size_t)(n0 + 4 * g + j) * M_K + m] = s[t][j] * inv[j];
    }
}

extern "C" void kernel_launch(void* const* d_in, const int* in_sizes, int n_in,
                              void* d_out, int out_size, void* d_ws, size_t ws_size,
                              hipStream_t stream)
{
    const float* q = (const float*)d_in[0];
    const float* k = (const float*)d_in[1];
    const float* W = (const float*)d_in[2];
    float* out = (float*)d_out;

    // ws layout (bytes):
    //   Qh 256K | Ql 256K | Kh 128K | Kl 128K | qn2 8K | kn2 4K
    unsigned char* base = (unsigned char*)d_ws;
    unsigned short* Qh = (unsigned short*)(base);
    unsigned short* Ql = (unsigned short*)(base + 262144);
    unsigned short* Kh = (unsigned short*)(base + 524288);
    unsigned short* Kl = (unsigned short*)(base + 655360);
    float* qn2 = (float*)(base + 786432);
    float* kn2 = (float*)(base + 794624);

    proj_split_kernel<<<(N_Q + M_K) / 32, 512, 0, stream>>>(
        q, k, W, Qh, Ql, Kh, Kl, qn2, kn2);
    score_kernel<<<N_Q / 16, 512, 0, stream>>>(
        Qh, Ql, Kh, Kl, qn2, kn2, out);
}

// Round 5
// 24.958 us; speedup vs baseline: 2.5148x; 2.5148x over previous
//
#include <hip/hip_runtime.h>
#include <hip/hip_bf16.h>
#include <math.h>

#define N_Q 2048
#define M_K 1024
#define DIN 128
#define DK  64

typedef __attribute__((ext_vector_type(8))) short short8;
typedef __attribute__((ext_vector_type(4))) float f32x4;
typedef __attribute__((ext_vector_type(4))) unsigned int u32x4;

// ---------------------------------------------------------------------------
// Kernel 1 (R2-proven structure): 768 blocks x 256 thr, one wave per row.
// Computes p = row @ W^T in fp32 (lane = output dim), then emits:
//   packed[row][lane] = (u32) bf16(hi) | bf16(lo)<<16   (hi=bf16(p), lo=bf16(p-hi))
// plus fp32 squared norm per row. Single coalesced dword store per row.
// ---------------------------------------------------------------------------
__global__ __launch_bounds__(256) void proj_kernel(
    const float* __restrict__ q, const float* __restrict__ k,
    const float* __restrict__ W,
    unsigned int* __restrict__ Qhl, unsigned int* __restrict__ Khl,
    float* __restrict__ qn2, float* __restrict__ kn2)
{
    __shared__ float W_lds[DK][DIN + 4];   // stride 132
    __shared__ float row_lds[4][DIN];
    const int tx = threadIdx.x;

    // cooperative load W: 2048 float4s, 8 per thread
    const float4* W4 = (const float4*)W;
    #pragma unroll
    for (int i = 0; i < 8; ++i) {
        int idx = tx + i * 256;            // float4 index
        float4 v = W4[idx];
        int r = idx >> 5, c = (idx & 31) * 4;
        *(float4*)&W_lds[r][c] = v;
    }

    const int wave = tx >> 6, lane = tx & 63;
    const int row  = blockIdx.x * 4 + wave;            // 0..3071
    const float* src = (row < N_Q) ? (q + (size_t)row * DIN)
                                   : (k + (size_t)(row - N_Q) * DIN);
    row_lds[wave][lane]      = src[lane];
    row_lds[wave][lane + 64] = src[lane + 64];
    __syncthreads();

    float acc = 0.f;
    #pragma unroll
    for (int d = 0; d < DIN; d += 4) {
        float4 wv = *(const float4*)&W_lds[lane][d];
        float4 rv = *(const float4*)&row_lds[wave][d];
        acc = fmaf(wv.x, rv.x, acc);
        acc = fmaf(wv.y, rv.y, acc);
        acc = fmaf(wv.z, rv.z, acc);
        acc = fmaf(wv.w, rv.w, acc);
    }

    // wave-reduce sum of squares -> norm^2 of the projected row (exact fp32)
    float sq = acc * acc;
    #pragma unroll
    for (int off = 32; off >= 1; off >>= 1)
        sq += __shfl_xor(sq, off, 64);

    // bf16 hi/lo split, packed into one dword
    __hip_bfloat16 hb = __float2bfloat16(acc);
    float hf = __bfloat162float(hb);
    __hip_bfloat16 lb = __float2bfloat16(acc - hf);
    unsigned int packed = (unsigned int)(*(unsigned short*)&hb)
                        | ((unsigned int)(*(unsigned short*)&lb) << 16);

    if (row < N_Q) {
        Qhl[(size_t)row * DK + lane] = packed;
        if (lane == 0) qn2[row] = sq;
    } else {
        const int m = row - N_Q;
        Khl[(size_t)m * DK + lane] = packed;
        if (lane == 0) kn2[m] = sq;
    }
}

// unpack 8 packed u32 (8 k-elems) -> hi short8 + lo short8 (bf16 bit patterns)
static __device__ __forceinline__ void unpack8(const unsigned int* __restrict__ p,
                                               short8& h, short8& l)
{
    u32x4 a = *(const u32x4*)p;
    u32x4 b = *(const u32x4*)(p + 4);
    u32x4 hu, lu;
    hu.x = (a.x & 0xFFFFu) | (a.y << 16);
    hu.y = (a.z & 0xFFFFu) | (a.w << 16);
    hu.z = (b.x & 0xFFFFu) | (b.y << 16);
    hu.w = (b.z & 0xFFFFu) | (b.w << 16);
    lu.x = (a.x >> 16) | (a.y & 0xFFFF0000u);
    lu.y = (a.z >> 16) | (a.w & 0xFFFF0000u);
    lu.z = (b.x >> 16) | (b.y & 0xFFFF0000u);
    lu.w = (b.z >> 16) | (b.w & 0xFFFF0000u);
    union { u32x4 u; short8 s; } ch, cl;
    ch.u = hu; cl.u = lu;
    h = ch.s; l = cl.s;
}

// ---------------------------------------------------------------------------
// Kernel 2 (structure validated in R4): 128 blocks x 512 thr (8 waves).
// Block = 16 q-rows x all 1024 m. Wave w owns m-strip [128w,128w+128):
// 8 tiles of 16x16 via mfma_f32_16x16x32_bf16; split-bf16 fp32 emulation
// (hi*hi + hi*lo + lo*hi). Frags unpacked in-register from packed u32 rows.
// C layout: col=lane&15 (m), row=4*(lane>>4)+reg (n)  [m89-verified].
// Epilogue: s=-0.5*sqrt(qn2+kn2-2c) -> row softmax (shfl within 16-lane
// groups + [16][8] LDS cross-wave reduce) -> dword stores.
// ---------------------------------------------------------------------------
__global__ __launch_bounds__(512) void score_kernel(
    const unsigned int* __restrict__ Qhl, const unsigned int* __restrict__ Khl,
    const float* __restrict__ qn2, const float* __restrict__ kn2,
    float* __restrict__ out)
{
    __shared__ float redmax[16][8];
    __shared__ float redsum[16][8];

    const int tx = threadIdx.x;
    const int w = tx >> 6, l = tx & 63;
    const int g = l >> 4, c = l & 15;
    const int n0 = blockIdx.x * 16;

    // A fragments: lane holds Q[n0+c][8g..8g+7] (k-step 0) / +32 (k-step 1)
    const unsigned int* qr = Qhl + (size_t)(n0 + c) * DK;
    short8 Ah0, Al0, Ah1, Al1;
    unpack8(qr + g * 8, Ah0, Al0);
    unpack8(qr + 32 + g * 8, Ah1, Al1);

    float qn[4];
    #pragma unroll
    for (int j = 0; j < 4; ++j) qn[j] = qn2[n0 + 4 * g + j];

    float s[8][4];
    #pragma unroll
    for (int t = 0; t < 8; ++t) {
        const int m = w * 128 + t * 16 + c;
        const unsigned int* kr = Khl + (size_t)m * DK;
        short8 Bh0, Bl0, Bh1, Bl1;
        unpack8(kr + g * 8, Bh0, Bl0);
        unpack8(kr + 32 + g * 8, Bh1, Bl1);

        f32x4 acc = {0.f, 0.f, 0.f, 0.f};
        acc = __builtin_amdgcn_mfma_f32_16x16x32_bf16(Ah0, Bh0, acc, 0, 0, 0);
        acc = __builtin_amdgcn_mfma_f32_16x16x32_bf16(Ah1, Bh1, acc, 0, 0, 0);
        acc = __builtin_amdgcn_mfma_f32_16x16x32_bf16(Ah0, Bl0, acc, 0, 0, 0);
        acc = __builtin_amdgcn_mfma_f32_16x16x32_bf16(Ah1, Bl1, acc, 0, 0, 0);
        acc = __builtin_amdgcn_mfma_f32_16x16x32_bf16(Al0, Bh0, acc, 0, 0, 0);
        acc = __builtin_amdgcn_mfma_f32_16x16x32_bf16(Al1, Bh1, acc, 0, 0, 0);

        const float kn = kn2[m];
        #pragma unroll
        for (int j = 0; j < 4; ++j) {
            float d2 = fmaxf(qn[j] + kn - 2.f * acc[j], 0.f);
            s[t][j] = -0.5f * sqrtf(d2);
        }
    }

    // row max over this wave's 128 cols, then across 8 waves via LDS
    #pragma unroll
    for (int j = 0; j < 4; ++j) {
        float m8 = s[0][j];
        #pragma unroll
        for (int t = 1; t < 8; ++t) m8 = fmaxf(m8, s[t][j]);
        m8 = fmaxf(m8, __shfl_xor(m8, 1, 64));
        m8 = fmaxf(m8, __shfl_xor(m8, 2, 64));
        m8 = fmaxf(m8, __shfl_xor(m8, 4, 64));
        m8 = fmaxf(m8, __shfl_xor(m8, 8, 64));
        if (c == 0) redmax[4 * g + j][w] = m8;
    }
    __syncthreads();

    float mx[4];
    #pragma unroll
    for (int j = 0; j < 4; ++j) {
        float m = redmax[4 * g + j][0];
        #pragma unroll
        for (int ww = 1; ww < 8; ++ww) m = fmaxf(m, redmax[4 * g + j][ww]);
        mx[j] = m;
    }

    // exp + row sum
    #pragma unroll
    for (int j = 0; j < 4; ++j) {
        float t8 = 0.f;
        #pragma unroll
        for (int t = 0; t < 8; ++t) {
            s[t][j] = __expf(s[t][j] - mx[j]);
            t8 += s[t][j];
        }
        t8 += __shfl_xor(t8, 1, 64);
        t8 += __shfl_xor(t8, 2, 64);
        t8 += __shfl_xor(t8, 4, 64);
        t8 += __shfl_xor(t8, 8, 64);
        if (c == 0) redsum[4 * g + j][w] = t8;
    }
    __syncthreads();

    float inv[4];
    #pragma unroll
    for (int j = 0; j < 4; ++j) {
        float t = 0.f;
        #pragma unroll
        for (int ww = 0; ww < 8; ++ww) t += redsum[4 * g + j][ww];
        inv[j] = 1.0f / t;
    }

    #pragma unroll
    for (int t = 0; t < 8; ++t) {
        const int m = w * 128 + t * 16 + c;
        #pragma unroll
        for (int j = 0; j < 4; ++j)
            out[(size_t)(n0 + 4 * g + j) * M_K + m] = s[t][j] * inv[j];
    }
}

extern "C" void kernel_launch(void* const* d_in, const int* in_sizes, int n_in,
                              void* d_out, int out_size, void* d_ws, size_t ws_size,
                              hipStream_t stream)
{
    const float* q = (const float*)d_in[0];
    const float* k = (const float*)d_in[1];
    const float* W = (const float*)d_in[2];
    float* out = (float*)d_out;

    // ws layout (bytes): Qhl 512K | Khl 256K | qn2 8K | kn2 4K
    unsigned char* base = (unsigned char*)d_ws;
    unsigned int* Qhl = (unsigned int*)(base);
    unsigned int* Khl = (unsigned int*)(base + 524288);
    float* qn2 = (float*)(base + 786432);
    float* kn2 = (float*)(base + 794624);

    proj_kernel<<<(N_Q + M_K) / 4, 256, 0, stream>>>(q, k, W, Qhl, Khl, qn2, kn2);
    score_kernel<<<N_Q / 16, 512, 0, stream>>>(Qhl, Khl, qn2, kn2, out);
}